// Round 1
// baseline (32148.010 us; speedup 1.0000x reference)
//
#include <hip/hip_runtime.h>
#include <stdint.h>

// Problem constants
#define TSTEPS 300
#define NGROUP 64            // batch slices of 16 rows
#define NSPLIT 4             // hidden-unit quarters (64 units each)
#define NBLK   (NGROUP * NSPLIT)   // 256 blocks = 1 per CU
#define NW     8             // waves per block
#define FRAGS  50            // weight frags per wave: L0 9ks*2tl + L1 16ks*2tl

typedef __bf16 bf16x8 __attribute__((ext_vector_type(8)));
typedef float  f32x4  __attribute__((ext_vector_type(4)));

__device__ __forceinline__ uint16_t f2bf(float f) {
  uint32_t u = __builtin_bit_cast(uint32_t, f);
  u += 0x7fffu + ((u >> 16) & 1u);   // RNE
  return (uint16_t)(u >> 16);
}
__device__ __forceinline__ float bf2f(uint16_t h) {
  uint32_t u = ((uint32_t)h) << 16;
  return __builtin_bit_cast(float, u);
}
__device__ __forceinline__ float sigm(float x) { return 1.0f / (1.0f + __expf(-x)); }
__device__ __forceinline__ float tanh_(float x) {
  float e = __expf(2.0f * x);
  return (e - 1.0f) / (e + 1.0f);
}

// ---------------------------------------------------------------------------
// P1: embedding gather + reshape(300,B,25) packed into MFMA A-frags.
// Xf[((t*64+g)*64+lane)*8+jj]; lane: m=lane&15 (batch row), k=(lane>>4)*8+jj.
// (unchanged from previous version)
// ---------------------------------------------------------------------------
__global__ void gather_x(const int* __restrict__ tok, const float* __restrict__ emb,
                         uint16_t* __restrict__ Xf) {
  int idx = blockIdx.x * 256 + threadIdx.x;       // < 300*64*512 = 9,830,400
  int t    = idx >> 15;
  int rem  = idx & 32767;
  int wg   = rem >> 9;
  int e512 = rem & 511;
  int lane = e512 >> 3;
  int jj   = e512 & 7;
  int m = lane & 15, quad = lane >> 4;
  int k = quad * 8 + jj;
  float v = 0.0f;
  if (k < 25) {
    int b = wg * 16 + m;
    int n = (t * 1024 + b) * 25 + k;              // flat index in [300,1024,25]
    int s  = n / 307200;                          // 1024*300
    int r2 = n - s * 307200;
    int bb = r2 / 300;
    int e  = r2 - bb * 300;
    int token = tok[bb * 25 + s];                 // input[bb][s]
    v = emb[(size_t)token * 300 + e];
  }
  Xf[idx] = f2bf(v);
}

// ---------------------------------------------------------------------------
// P2: pack weights into per-(s, wave) register streams of 50 B-frags.
// Wp[(((s*8+w)*50+f)*64+lane)*8+jj]; lane: n=lane&15, k=(lane>>4)*8+jj.
// f<18: layer0 (ks=f>>1, tl=f&1); f>=18: layer1. Wave w: gate nt=w>>1,
// husub = (w&1)*32 + tl*16 + nl. n = nt*256 + s*64 + husub.
// ---------------------------------------------------------------------------
__global__ void pack_w(const float* __restrict__ Wih0, const float* __restrict__ Whh0,
                       const float* __restrict__ Wih1, const float* __restrict__ Whh1,
                       uint16_t* __restrict__ Wp) {
  int idx = blockIdx.x * 256 + threadIdx.x;       // < 4*8*50*512 = 819,200
  int e  = idx & 511;
  int fg = idx >> 9;                              // 0..6399
  int f  = fg % FRAGS;
  int wv = (fg / FRAGS) & 7;
  int s  = fg / (FRAGS * 8);
  int lane = e >> 3, jj = e & 7;
  int nl = lane & 15, kk = (lane >> 4) * 8 + jj;
  int ks, tl;
  bool l1 = (f >= 18);
  if (!l1) { ks = f >> 1; tl = f & 1; }
  else     { int f1 = f - 18; ks = f1 >> 1; tl = f1 & 1; }
  int n = (wv >> 1) * 256 + s * 64 + (wv & 1) * 32 + tl * 16 + nl;
  float v;
  if (!l1) {
    if (ks == 0) v = (kk < 25) ? Wih0[n * 25 + kk] : 0.0f;
    else         v = Whh0[n * 256 + (ks - 1) * 32 + kk];
  } else {
    int k = ks * 32 + kk;
    v = (k < 256) ? Wih1[n * 256 + k] : Whh1[n * 256 + (k - 256)];
  }
  Wp[idx] = f2bf(v);
}

// ---------------------------------------------------------------------------
// Main cooperative kernel: 256 blocks x 512 threads (8 waves), 1 block/CU.
// Block (g,s): batch rows 16g..16g+15, hidden units s*64..s*64+63 (both
// layers, all 4 gates). All weights (50 frags/wave = 200 VGPR) live in
// registers for the whole 300-step loop -> zero weight re-fetch.
// Per step the 4 blocks of a group exchange their 16x64 bf16 h-slices via a
// ping-pong global buffer + release/acquire flags (same-XCD via bid%8).
// ---------------------------------------------------------------------------
__global__ __launch_bounds__(512, 2) void lstm_main(
    const float* __restrict__ h0in, const float* __restrict__ c0in,
    const float* __restrict__ fcw,  const float* __restrict__ fcb,
    const float* __restrict__ decw, const float* __restrict__ decb,
    const float* __restrict__ bih0, const float* __restrict__ bhh0,
    const float* __restrict__ bih1, const float* __restrict__ bhh1,
    const uint16_t* __restrict__ Xf, const uint16_t* __restrict__ Wp,
    uint16_t* __restrict__ xh0, uint16_t* __restrict__ xh1,
    int* __restrict__ flags, float* __restrict__ out)
{
  __shared__ uint16_t h0s[16][264];   // full h0 state (bf16), stride 264: 2-way banks
  __shared__ uint16_t h1s[16][264];   // full h1 state
  __shared__ float    gl[16][260];    // gate tiles [row][gate*64+hu], pad 260
  __shared__ float    fcs[16][10];

  const int bid  = blockIdx.x;
  const int s    = bid >> 6;          // hidden quarter 0..3
  const int g    = bid & 63;          // batch slice 0..63
  const int tid  = threadIdx.x;
  const int w    = tid >> 6;          // wave 0..7
  const int lane = tid & 63;
  const int jl   = lane & 15;
  const int quad = lane >> 4;

  // ---- load all weights into registers (once) ----
  const uint4* pw = (const uint4*)Wp + ((size_t)(s * NW + w) * FRAGS) * 64 + lane;
  bf16x8 wr[FRAGS];
#pragma unroll
  for (int i = 0; i < FRAGS; i++)
    wr[i] = __builtin_bit_cast(bf16x8, pw[i * 64]);

  // biases for this wave's two 16-col tiles (per-lane, replicated over rows)
  const int ncol = (w >> 1) * 256 + s * 64 + (w & 1) * 32 + jl;
  const float bA0 = bih0[ncol]      + bhh0[ncol];
  const float bA1 = bih0[ncol + 16] + bhh0[ncol + 16];
  const float bB0 = bih1[ncol]      + bhh1[ncol];
  const float bB1 = bih1[ncol + 16] + bhh1[ncol + 16];

  // ---- init LDS h state from h0 input (full 256 cols) ----
  for (int idx = tid; idx < 16 * 256; idx += 512) {
    int r = idx >> 8, k = idx & 255;
    size_t b = (size_t)g * 16 + r;
    h0s[r][k] = f2bf(h0in[b * 256 + k]);
    h1s[r][k] = f2bf(h0in[262144 + b * 256 + k]);
  }

  // ---- updater role: thread owns entries (ur,uh) and (ur+8,uh) ----
  const int ur = tid >> 6;            // 0..7
  const int uh = tid & 63;            // local hidden unit
  const size_t cb = ((size_t)g * 16 + ur) * 256 + s * 64 + uh;
  float c0_a = c0in[cb],           c0_b = c0in[cb + 8 * 256];
  float c1_a = c0in[262144 + cb],  c1_b = c0in[262144 + cb + 8 * 256];
  float h0_a = 0.f, h0_b = 0.f, h1_a = 0.f, h1_b = 0.f;

  // ---- copier role: tids 0..383 each move one uint4 of a peer slice ----
  const int ci = tid & 127;           // uint4 index within 2KB slice
  const int cs = tid >> 7;            // 0..3; active if <3
  const int sp = (s + 1 + cs) & 3;    // peer quarter
  const int cr = ci >> 3;             // row
  const int cc = (ci & 7) * 8;        // col start within 64

  __syncthreads();

  const uint4* px = (const uint4*)Xf;
  uint4 xf = px[((size_t)0 * 64 + g) * 64 + lane];   // x A-frag for t=0

  const int gcb = (w >> 1) * 64 + (w & 1) * 32 + jl; // local gate col for gl

#pragma unroll 1
  for (int t = 0; t < TSTEPS; t++) {
    const size_t xpar = ((size_t)((t & 1) * 64 + g) * 4);

    // ================= [A] layer-0 MFMAs =================
    f32x4 acc0 = {bA0, bA0, bA0, bA0};
    f32x4 acc1 = {bA1, bA1, bA1, bA1};
    {
      bf16x8 a = __builtin_bit_cast(bf16x8, xf);     // ks=0: x (K 0..31)
#pragma unroll
      for (int ks = 0; ks <= 8; ks++) {
        bf16x8 an;
        if (ks < 8) an = *(const bf16x8*)&h0s[jl][ks * 32 + quad * 8];
        acc0 = __builtin_amdgcn_mfma_f32_16x16x32_bf16(a, wr[2 * ks],     acc0, 0, 0, 0);
        acc1 = __builtin_amdgcn_mfma_f32_16x16x32_bf16(a, wr[2 * ks + 1], acc1, 0, 0, 0);
        a = an;
      }
    }
#pragma unroll
    for (int r = 0; r < 4; r++) {
      gl[quad * 4 + r][gcb]      = acc0[r];
      gl[quad * 4 + r][gcb + 16] = acc1[r];
    }
    __syncthreads();                               // b1: gates visible

    // ================= [B] layer-0 cell update =================
    {
      float i1 = sigm (gl[ur][uh]);
      float f1 = sigm (gl[ur][64 + uh]);
      float g1 = tanh_(gl[ur][128 + uh]);
      float o1 = sigm (gl[ur][192 + uh]);
      c0_a = f1 * c0_a + i1 * g1;
      h0_a = o1 * tanh_(c0_a);
      float i2 = sigm (gl[ur + 8][uh]);
      float f2 = sigm (gl[ur + 8][64 + uh]);
      float g2 = tanh_(gl[ur + 8][128 + uh]);
      float o2 = sigm (gl[ur + 8][192 + uh]);
      c0_b = f2 * c0_b + i2 * g2;
      h0_b = o2 * tanh_(c0_b);
      uint16_t ha = f2bf(h0_a), hb = f2bf(h0_b);
      h0s[ur][s * 64 + uh]     = ha;
      h0s[ur + 8][s * 64 + uh] = hb;
      size_t xb = (xpar + s) * 1024;
      xh0[xb + ur * 64 + uh]       = ha;
      xh0[xb + (ur + 8) * 64 + uh] = hb;
    }
    __threadfence();
    __syncthreads();                               // b2: slice written

    // ================= [C] signal + fetch peer h0 slices =================
    if (tid == 0)
      __hip_atomic_store(&flags[s * 64 + g], t + 1,
                         __ATOMIC_RELEASE, __HIP_MEMORY_SCOPE_AGENT);
    if (cs < 3) {
      int* fp = &flags[sp * 64 + g];
      while (__hip_atomic_load(fp, __ATOMIC_ACQUIRE, __HIP_MEMORY_SCOPE_AGENT) < t + 1)
        __builtin_amdgcn_s_sleep(1);
      const uint4* src = (const uint4*)xh0 + (xpar + sp) * 128;
      uint4 v = src[ci];
      *(uint4*)&h0s[cr][sp * 64 + cc] = v;
    }
    __syncthreads();                               // b3: h0(t) complete in LDS

    // ================= [D] layer-1 MFMAs (+ x prefetch) =================
    {
      int tn = (t < TSTEPS - 1) ? t + 1 : t;
      xf = px[((size_t)tn * 64 + g) * 64 + lane];  // prefetch next x
    }
    acc0 = (f32x4){bB0, bB0, bB0, bB0};
    acc1 = (f32x4){bB1, bB1, bB1, bB1};
    {
      bf16x8 a = *(const bf16x8*)&h0s[jl][quad * 8];   // ks=0: h0_new
#pragma unroll
      for (int ks = 0; ks < 16; ks++) {
        bf16x8 an;
        if (ks < 15) {
          int ksn = ks + 1;
          const uint16_t* ab = (ksn < 8) ? &h0s[jl][ksn * 32 + quad * 8]
                                         : &h1s[jl][(ksn - 8) * 32 + quad * 8];
          an = *(const bf16x8*)ab;
        }
        acc0 = __builtin_amdgcn_mfma_f32_16x16x32_bf16(a, wr[18 + 2 * ks],     acc0, 0, 0, 0);
        acc1 = __builtin_amdgcn_mfma_f32_16x16x32_bf16(a, wr[18 + 2 * ks + 1], acc1, 0, 0, 0);
        a = an;
      }
    }
#pragma unroll
    for (int r = 0; r < 4; r++) {
      gl[quad * 4 + r][gcb]      = acc0[r];
      gl[quad * 4 + r][gcb + 16] = acc1[r];
    }
    __syncthreads();                               // b4

    // ================= [E] layer-1 cell update =================
    {
      float i1 = sigm (gl[ur][uh]);
      float f1 = sigm (gl[ur][64 + uh]);
      float g1 = tanh_(gl[ur][128 + uh]);
      float o1 = sigm (gl[ur][192 + uh]);
      c1_a = f1 * c1_a + i1 * g1;
      h1_a = o1 * tanh_(c1_a);
      float i2 = sigm (gl[ur + 8][uh]);
      float f2 = sigm (gl[ur + 8][64 + uh]);
      float g2 = tanh_(gl[ur + 8][128 + uh]);
      float o2 = sigm (gl[ur + 8][192 + uh]);
      c1_b = f2 * c1_b + i2 * g2;
      h1_b = o2 * tanh_(c1_b);
      uint16_t ha = f2bf(h1_a), hb = f2bf(h1_b);
      h1s[ur][s * 64 + uh]     = ha;
      h1s[ur + 8][s * 64 + uh] = hb;
      size_t xb = (xpar + s) * 1024;
      xh1[xb + ur * 64 + uh]       = ha;
      xh1[xb + (ur + 8) * 64 + uh] = hb;
    }
    __threadfence();
    __syncthreads();                               // b5

    // ================= [F] signal + fetch peer h1 slices =================
    if (tid == 0)
      __hip_atomic_store(&flags[256 + s * 64 + g], t + 1,
                         __ATOMIC_RELEASE, __HIP_MEMORY_SCOPE_AGENT);
    if (cs < 3) {
      int* fp = &flags[256 + sp * 64 + g];
      while (__hip_atomic_load(fp, __ATOMIC_ACQUIRE, __HIP_MEMORY_SCOPE_AGENT) < t + 1)
        __builtin_amdgcn_s_sleep(1);
      const uint4* src = (const uint4*)xh1 + (xpar + sp) * 128;
      uint4 v = src[ci];
      *(uint4*)&h1s[cr][sp * 64 + cc] = v;
    }
    __syncthreads();                               // b6: h1(t) complete in LDS
  }

  // ================= epilogue =================
  // out layout: decoded.T [2,1024] | h [2,1024,256] | c [2,1024,256]
  float* outH = out + 2048;
  float* outC = out + 2048 + 524288;
  {
    size_t ba = (size_t)g * 16 + ur;
    size_t oa = ba * 256 + s * 64 + uh;
    outH[oa]           = h0_a;
    outH[262144 + oa]  = h1_a;
    outC[oa]           = c0_a;
    outC[262144 + oa]  = c1_a;
    size_t ob = oa + 8 * 256;
    outH[ob]           = h0_b;
    outH[262144 + ob]  = h1_b;
    outC[ob]           = c0_b;
    outC[262144 + ob]  = c1_b;
  }
  // fc + decoded: one block per group (s==0); h1s holds full final h1
  if (s == 0) {
    if (tid < 160) {
      int r = tid / 10, j = tid - r * 10;
      float acc = fcb[j];
      for (int k = 0; k < 256; k++)
        acc += bf2f(h1s[r][k]) * fcw[j * 256 + k];
      fcs[r][j] = fmaxf(acc, 0.0f);
    }
    __syncthreads();
    if (tid < 32) {
      int r = tid & 15, m = tid >> 4;
      float d = decb[m];
#pragma unroll
      for (int q = 0; q < 10; q++) d += fcs[r][q] * decw[m * 10 + q];
      out[(size_t)m * 1024 + g * 16 + r] = d;
    }
  }
}

// ---------------------------------------------------------------------------
extern "C" void kernel_launch(void* const* d_in, const int* in_sizes, int n_in,
                              void* d_out, int out_size, void* d_ws, size_t ws_size,
                              hipStream_t stream) {
  const int*   tok  = (const int*)d_in[0];
  const float* h0   = (const float*)d_in[1];
  const float* c0   = (const float*)d_in[2];
  const float* emb  = (const float*)d_in[3];
  const float* fcw  = (const float*)d_in[4];
  const float* fcb  = (const float*)d_in[5];
  const float* decw = (const float*)d_in[6];
  const float* decb = (const float*)d_in[7];
  const float* Wih0 = (const float*)d_in[8];
  const float* Whh0 = (const float*)d_in[9];
  const float* bih0 = (const float*)d_in[10];
  const float* bhh0 = (const float*)d_in[11];
  const float* Wih1 = (const float*)d_in[12];
  const float* Whh1 = (const float*)d_in[13];
  const float* bih1 = (const float*)d_in[14];
  const float* bhh1 = (const float*)d_in[15];

  uint16_t* Xf   = (uint16_t*)d_ws;        // 9,830,400 bf16 = 19.66 MB
  uint16_t* Wpk  = Xf  + 9830400;          //   819,200 bf16 =  1.64 MB
  uint16_t* xh0  = Wpk + 819200;           //   524,288 bf16 =  1.05 MB (2 par x 64g x 4s x 1024)
  uint16_t* xh1  = xh0 + 524288;           //   524,288 bf16
  int*      flg  = (int*)(xh1 + 524288);   //   512 ints

  hipMemsetAsync(flg, 0, 512 * sizeof(int), stream);
  gather_x<<<38400, 256, 0, stream>>>(tok, emb, Xf);
  pack_w<<<3200, 256, 0, stream>>>(Wih0, Whh0, Wih1, Whh1, Wpk);

  float* outp = (float*)d_out;
  void* args[16] = {
    (void*)&h0,  (void*)&c0,  (void*)&fcw,  (void*)&fcb,
    (void*)&decw,(void*)&decb,(void*)&bih0, (void*)&bhh0,
    (void*)&bih1,(void*)&bhh1,(void*)&Xf,   (void*)&Wpk,
    (void*)&xh0, (void*)&xh1, (void*)&flg,  (void*)&outp
  };
  hipLaunchCooperativeKernel((const void*)lstm_main, dim3(NBLK), dim3(512),
                             args, 0, stream);
}